// Round 9
// baseline (262.871 us; speedup 1.0000x reference)
//
#include <hip/hip_runtime.h>
#include <math.h>

#define BB 4
#define LQ 8400
#define NH 8
#define LVTOT 8500
#define HD 32
#define PLANE_USH 544000   // 8500 pairs x 64 ushorts (2 parity copies of 4250)

typedef __attribute__((ext_vector_type(8))) short short8;
typedef __attribute__((ext_vector_type(4))) float f32x4;
typedef __attribute__((ext_vector_type(2))) _Float16 half2_t;
typedef __attribute__((ext_vector_type(2))) __fp16 fp16x2_t;
typedef unsigned short ushort_t;

__device__ __forceinline__ ushort_t f2bf(float f) {
    union { float f; unsigned u; } v; v.f = f;
    unsigned r = v.u + 0x7fffu + ((v.u >> 16) & 1u);   // RNE
    return (ushort_t)(r >> 16);
}
__device__ __forceinline__ float bflo(unsigned u) {
    union { unsigned u; float f; } x; x.u = u << 16; return x.f;
}
__device__ __forceinline__ float bfhi(unsigned u) {
    union { unsigned u; float f; } x; x.u = u & 0xffff0000u; return x.f;
}
__device__ __forceinline__ half2_t ash2(unsigned u) {
    union { unsigned u; half2_t h; } x; x.u = u; return x.h;
}
__device__ __forceinline__ unsigned pk2u(fp16x2_t h) {
    union { fp16x2_t h; unsigned u; } x; x.h = h; return x.u;
}

// async global->LDS DMA, 16 B per lane (wave-uniform LDS base + lane*16)
__device__ __forceinline__ void dma16(const ushort_t* g, ushort_t* l) {
    __builtin_amdgcn_global_load_lds(
        (const __attribute__((address_space(1))) void*)g,
        (__attribute__((address_space(3))) void*)l, 16, 0, 0);
}

// level decomposition of a pixel index (0..8499) -> pair-space geometry
__device__ __forceinline__ void lvl_decomp(int pix, int& lb, int& y, int& x,
                                           int& rowp) {
    if (pix < 6400)      { y = pix / 80;            x = pix - y * 80;  rowp = 40; lb = 0; }
    else if (pix < 8000) { int r = pix - 6400; y = r / 40; x = r - y * 40; rowp = 20; lb = 3200; }
    else if (pix < 8400) { int r = pix - 8000; y = r / 20; x = r - y * 20; rowp = 10; lb = 4000; }
    else                 { int r = pix - 8400; y = r / 10; x = r - y * 10; rowp = 5;  lb = 4200; }
}

// ---------------------------------------------------------------------------
// Merged prep: blocks [0,8500) cast value, [8500,16900) cast query,
// [16900,17796) build BT (transposed bf16 weights, 896 rows x 256 k).
// ---------------------------------------------------------------------------
__global__ __launch_bounds__(256) void prep_all(
    const float* __restrict__ value, const float* __restrict__ query,
    const float* __restrict__ Wv, const float* __restrict__ Woff,
    const float* __restrict__ Wattn, const float* __restrict__ Wo,
    ushort_t* __restrict__ value_b, ushort_t* __restrict__ query_b,
    ushort_t* __restrict__ BT)
{
    const int bid = blockIdx.x;
    if (bid < 16900) {
        const float* src = (bid < 8500) ? value : query;
        ushort_t* dst = (bid < 8500) ? value_b : query_b;
        int i = (bid < 8500 ? bid : bid - 8500) * 256 + threadIdx.x;
        float4 f = ((const float4*)src)[i];
        ushort4 o;
        o.x = f2bf(f.x); o.y = f2bf(f.y); o.z = f2bf(f.z); o.w = f2bf(f.w);
        ((ushort4*)dst)[i] = o;
    } else {
        int idx = (bid - 16900) * 256 + threadIdx.x;   // 896*256
        int r = idx >> 8, k = idx & 255;
        float v;
        if (r < 256) v = Wv[k * 256 + r];
        else if (r < 640) {
            int n = r - 256;
            v = (n < 256) ? Woff[k * 256 + n] : Wattn[k * 128 + (n - 256)];
        } else v = Wo[k * 256 + (r - 640)];
        BT[idx] = f2bf(v);
    }
}

// ---------------------------------------------------------------------------
// GEMM core v3: 256x128 tile, 8 waves (4M x 2N), BK=64, serial proven
// 2-barrier loop. Per-element staged bytes and barrier-drains HALVED vs the
// 128x128 core. Staging via global_load_lds dwordx4 w/ XOR source swizzle.
// ---------------------------------------------------------------------------
__device__ __forceinline__ void gemm_core256(
    const ushort_t* __restrict__ A, const ushort_t* __restrict__ B, int M,
    int m0, int n0, ushort_t* Asl, ushort_t* Bsl, f32x4 acc[4][4])
{
    const int tid  = threadIdx.x;
    const int wave = tid >> 6, lane = tid & 63;
    const int quad = lane >> 4, mr = lane & 15;
    const int wm   = (wave >> 1) * 64, wn = (wave & 1) * 64;
    const int oct  = lane >> 3;       // 0..7 row-in-wave-slab
    const int bseg = lane & 7;        // physical 16B slot within row

    for (int k0 = 0; k0 < 256; k0 += 64) {
        __syncthreads();              // prior iteration's reads done
        #pragma unroll
        for (int i = 0; i < 4; i++) {                 // A: 256 rows
            int m  = i * 64 + wave * 8 + oct;
            int gs = bseg ^ (m & 7);
            int am = min(m0 + m, M - 1);
            dma16(A + (size_t)am * 256 + k0 + gs * 8,
                  Asl + (i * 64 + wave * 8) * 64 + lane * 8);
        }
        #pragma unroll
        for (int i = 0; i < 2; i++) {                 // B: 128 rows
            int n  = i * 64 + wave * 8 + oct;
            int gs = bseg ^ (n & 7);
            int bn = n0 + n;
            dma16(B + (size_t)bn * 256 + k0 + gs * 8,
                  Bsl + (i * 64 + wave * 8) * 64 + lane * 8);
        }
        __syncthreads();              // DMA landed
        #pragma unroll
        for (int ks = 0; ks < 2; ks++) {
            short8 af[4], bf[4];
            const int ksl = ks * 4 + quad;
            #pragma unroll
            for (int i = 0; i < 4; i++) {
                int m = wm + i * 16 + mr;
                af[i] = *(const short8*)&Asl[m * 64 + (ksl ^ (m & 7)) * 8];
                int n = wn + i * 16 + mr;
                bf[i] = *(const short8*)&Bsl[n * 64 + (ksl ^ (n & 7)) * 8];
            }
            #pragma unroll
            for (int i = 0; i < 4; i++)
                #pragma unroll
                for (int j = 0; j < 4; j++)
                    acc[i][j] = __builtin_amdgcn_mfma_f32_16x16x32_bf16(
                        af[i], bf[j], acc[i][j], 0, 0, 0);
        }
    }
}

// ---------------------------------------------------------------------------
// Fused GEMM1 (value->vperm f16 pair-interleaved x2 parity, 266 blocks) +
// GEMM2 (query->off/awl, 396 blocks). 256x128 tiles. Epilogue repacks acc
// into a 128x128 LDS tile in TWO row-halves (waves 0-3 then 4-7), then
// stores coalesced: mode1 row-major 16B; mode0 pair-major units + 2x128
// boundary scatters per half. Wrap pairs skipped (never read).
// ---------------------------------------------------------------------------
__global__ __launch_bounds__(512, 4) void gemm_fused(
    const ushort_t* __restrict__ Av, const ushort_t* __restrict__ Aq,
    const ushort_t* __restrict__ BT,
    const float* __restrict__ bv, const float* __restrict__ boff,
    const float* __restrict__ battn,
    ushort_t* __restrict__ vperm, ushort_t* __restrict__ off_b,
    ushort_t* __restrict__ awl_b)
{
    __shared__ ushort_t smem[24576];   // A 256x64 | B 128x64; epi: 128x128 tile
    ushort_t* Asl = smem;
    ushort_t* Bsl = smem + 16384;

    const int bid = blockIdx.x;
    int mode, m0, n0, M;
    const ushort_t *A, *B;
    if (bid < 266) { mode = 0; m0 = (bid >> 1) * 256; n0 = (bid & 1) * 128;
                     A = Av; B = BT; M = 34000; }
    else { int b2 = bid - 266;
           mode = 1; m0 = (b2 / 3) * 256; n0 = (b2 % 3) * 128;
           A = Aq; B = BT + 65536; M = 33600; }

    f32x4 acc[4][4];
    #pragma unroll
    for (int i = 0; i < 4; i++)
        #pragma unroll
        for (int j = 0; j < 4; j++) acc[i][j] = (f32x4){0.f, 0.f, 0.f, 0.f};

    gemm_core256(A, B, M, m0, n0, Asl, Bsl, acc);

    const int tid  = threadIdx.x;
    const int wave = tid >> 6, lane = tid & 63;
    const int quad = lane >> 4, mr = lane & 15;
    const int wm   = (wave >> 1) * 64, wn = (wave & 1) * 64;
    const int whalf = wave >> 2;       // which 128-row half this wave owns

    __syncthreads();                   // K-loop LDS reads done

    for (int half = 0; half < 2; half++) {
        // ---- step 1: owning waves write acc (+bias, cvt) into swizzled tile
        if (whalf == half) {
            #pragma unroll
            for (int i = 0; i < 4; i++) {
                #pragma unroll
                for (int j = 0; j < 4; j++) {
                    const int lc = wn + j * 16 + mr;
                    const int c  = n0 + lc;
                    const float bias = (mode == 0) ? bv[c]
                                      : (c < 256 ? boff[c] : battn[c - 256]);
                    #pragma unroll
                    for (int reg = 0; reg < 4; reg++) {
                        const int rl = (wm & 127) + i * 16 + quad * 4 + reg;
                        float val = acc[i][j][reg] + bias;
                        ushort_t u;
                        if (mode == 0) { union { _Float16 h; ushort_t u; } cv;
                                         cv.h = (_Float16)val; u = cv.u; }
                        else u = f2bf(val);
                        smem[rl * 128 + (lc ^ ((rl & 3) << 3))] = u;
                    }
                }
            }
        }
        __syncthreads();

        // ---- step 2: all 512 threads store this half coalesced
        const int m0h = m0 + half * 128;
        if (mode == 1) {
            #pragma unroll
            for (int k = 0; k < 4; k++) {
                int sid = k * 512 + tid;            // 2048 x 16B
                int rl = sid >> 4, cc = (sid & 15) * 8;
                int row = m0h + rl;
                if (row >= M) continue;
                uint4 v = *(const uint4*)&smem[rl * 128 + (cc ^ ((rl & 3) << 3))];
                if (n0 < 256) *(uint4*)&off_b[(size_t)row * 256 + n0 + cc] = v;
                else          *(uint4*)&awl_b[(size_t)row * 128 + cc] = v;
            }
        } else {
            const int hb = n0 >> 5;                 // head base: 0 or 4
            #pragma unroll
            for (int k = 0; k < 8; k++) {
                int sid = k * 512 + tid;            // 4096 slots, 127*32 used
                int unit = sid >> 5;
                if (unit >= 127) continue;
                int sub = sid & 31;
                int hh = sub >> 3, q = sub & 7;
                int copy = (unit >= 64) ? 1 : 0;
                int t = copy ? ((unit - 64) * 2 + 1) : (unit * 2);
                int row = m0h + t;
                if (row + 1 >= 34000) continue;     // need both pixels
                int b = row / LVTOT, pix = row - b * LVTOT;
                int lb, y, x, rowp;
                lvl_decomp(pix, lb, y, x, rowp);
                if (copy && x >= 2 * rowp - 1) continue;   // wrap pair
                int p = x >> 1;
                int pidx = copy * 4250 + lb + y * rowp + p;
                int h = hb + hh;
                uint2 a  = *(const uint2*)&smem[t * 128 +
                              ((hh * 32 + q * 4) ^ ((t & 3) << 3))];
                uint2 b2 = *(const uint2*)&smem[(t + 1) * 128 +
                              ((hh * 32 + q * 4) ^ (((t + 1) & 3) << 3))];
                uint4 o;
                o.x = (a.x & 0xffffu) | (b2.x << 16);
                o.y = (a.x >> 16)     | (b2.x & 0xffff0000u);
                o.z = (a.y & 0xffffu) | (b2.y << 16);
                o.w = (a.y >> 16)     | (b2.y & 0xffff0000u);
                *(uint4*)((char*)(vperm + (size_t)(b * NH + h) * PLANE_USH)
                          + (size_t)pidx * 128 + q * 16) = o;
            }
            // boundary scatters: t=0 -> slot1 of left pair; t=127 -> slot0
            if (tid < 256) {
                int pixsel = tid >> 7;              // 0: t=0, 1: t=127
                int rem = tid & 127;
                int hh = rem >> 5, d = rem & 31;
                int t = pixsel ? 127 : 0;
                int row = m0h + t;
                if (row < 34000) {
                    int b = row / LVTOT, pix = row - b * LVTOT;
                    int lb, y, x, rowp;
                    lvl_decomp(pix, lb, y, x, rowp);
                    bool doit; int p, slot;
                    if (!pixsel) { doit = (x >= 2);            p = (x - 2) >> 1; slot = 1; }
                    else         { doit = (x < 2 * rowp - 1);  p = (x - 1) >> 1; slot = 0; }
                    if (doit) {
                        int pidx = 4250 + lb + y * rowp + p;
                        int h = hb + hh;
                        vperm[(size_t)(b * NH + h) * PLANE_USH
                              + (size_t)pidx * 64 + d * 2 + slot] =
                            smem[t * 128 + ((hh * 32 + d) ^ ((t & 3) << 3))];
                    }
                }
            }
        }
        __syncthreads();
    }
}

// ---------------------------------------------------------------------------
// GEMM3: sampled(bf16) @ Wo + bo -> out fp32. 256x128 tiles, direct stores.
// ---------------------------------------------------------------------------
__global__ __launch_bounds__(512, 4) void gemm_out(
    const ushort_t* __restrict__ A, const ushort_t* __restrict__ BT,
    const float* __restrict__ bo, float* __restrict__ out)
{
    __shared__ ushort_t Asl[256 * 64];
    __shared__ ushort_t Bsl[128 * 64];

    const int m0 = (blockIdx.x >> 1) * 256;    // adjacency swizzle (132x2)
    const int n0 = (blockIdx.x & 1) * 128;
    const int M = 33600;

    f32x4 acc[4][4];
    #pragma unroll
    for (int i = 0; i < 4; i++)
        #pragma unroll
        for (int j = 0; j < 4; j++) acc[i][j] = (f32x4){0.f, 0.f, 0.f, 0.f};

    gemm_core256(A, BT, M, m0, n0, Asl, Bsl, acc);

    const int tid  = threadIdx.x;
    const int wave = tid >> 6, lane = tid & 63;
    const int quad = lane >> 4, mr = lane & 15;
    const int wm   = (wave >> 1) * 64, wn = (wave & 1) * 64;

    #pragma unroll
    for (int i = 0; i < 4; i++) {
        const int rbase = m0 + wm + i * 16 + quad * 4;
        #pragma unroll
        for (int j = 0; j < 4; j++) {
            const int c = n0 + wn + j * 16 + mr;
            #pragma unroll
            for (int reg = 0; reg < 4; reg++) {
                int row = rbase + reg;
                if (row >= M) continue;
                out[(size_t)row * 256 + c] = acc[i][j][reg] + bo[c];
            }
        }
    }
}

// ---------------------------------------------------------------------------
// Sampler v10 (unchanged): pair-interleaved gathers, plane-locality blocks
// (b, h, 32-query chunk), h = bid&7 XCD-pinned.
// ---------------------------------------------------------------------------
__global__ __launch_bounds__(256) void msda_sample(
    const ushort_t* __restrict__ vperm, const ushort_t* __restrict__ off,
    const ushort_t* __restrict__ awl, const float* __restrict__ refp,
    ushort_t* __restrict__ sampled)
{
    __shared__ int4 s_wi[16 * 33];   // (wt f16x2, wb f16x2, off_top, off_bot)

    const int tid = threadIdx.x;
    const int bid = blockIdx.x;
    const int h   = bid & 7;          // XCD-pinned head
    const int r   = bid >> 3;         // 0..1051
    const int b   = r / 263;
    const int c   = r - b * 263;      // chunk within batch
    const int q0b = c * 32;           // first query (within batch b)
    const size_t bq0 = (size_t)b * LQ + q0b;

    const int Hs[4]    = {80, 40, 20, 10};
    const int pbase[4] = {0, 3200, 4000, 4200};

    #pragma unroll
    for (int it = 0; it < 2; it++) {
        const int s  = it * 256 + tid;
        const int ql = s >> 4, lp = s & 15;
        const int l  = lp >> 2;
        const int qv = (q0b + ql < LQ) ? ql : 0;   // clamp tail chunk reads
        const size_t bq = bq0 + qv;
        const int Wl = Hs[l];

        unsigned od = *(const unsigned*)(off + bq * 256 + h * 32 + lp * 2);
        float ox = bflo(od), oy = bfhi(od);
        float lgt = bflo((unsigned)awl[bq * 128 + h * 16 + lp]);
        // softmax over the 16-lane (q) group, no max pass (bounded logits)
        float e = __expf(lgt);
        float sum = e;
        sum += __shfl_xor(sum, 1, 16);
        sum += __shfl_xor(sum, 2, 16);
        sum += __shfl_xor(sum, 4, 16);
        sum += __shfl_xor(sum, 8, 16);
        float aw = e * __builtin_amdgcn_rcpf(sum);

        float2 rp = *(const float2*)(refp + bq * 8 + l * 2);
        float x = rp.x * (float)Wl + ox - 0.5f;
        float y = rp.y * (float)Wl + oy - 0.5f;
        float x0f = floorf(x), y0f = floorf(y);
        float wx = x - x0f, wy = y - y0f;
        int x0 = (int)x0f, y0 = (int)y0f;
        float hx0 = ((x0 >= 0) & (x0 < Wl)) ? (1.f - wx) : 0.f;
        float hx1 = ((x0 + 1 >= 0) & (x0 + 1 < Wl)) ? wx : 0.f;
        float vy0w = ((y0 >= 0) & (y0 < Wl)) ? (1.f - wy) * aw : 0.f;
        float vy1w = ((y0 + 1 >= 0) & (y0 + 1 < Wl)) ? wy * aw : 0.f;
        // fold borders into a valid adjacent pair (px, px+1)
        int px = min(max(x0, 0), Wl - 2);
        float pl, pr;
        if (x0 < px)      { pl = hx1; pr = 0.f; }   // x0 left of grid
        else if (x0 > px) { pl = 0.f; pr = hx0; }   // x0 == Wl-1
        else              { pl = hx0; pr = hx1; }
        int cy0 = min(max(y0, 0), Wl - 1);
        int cy1 = min(max(y0 + 1, 0), Wl - 1);
        const int copy = px & 1;
        const int p    = copy ? ((px - 1) >> 1) : (px >> 1);
        const int rowp = Wl >> 1;
        const int cb   = copy * 4250 + pbase[l] + p;
        const int otop = (cb + cy0 * rowp) << 7;    // pair byte offsets
        const int obot = (cb + cy1 * rowp) << 7;
        unsigned wt = pk2u(__builtin_amdgcn_cvt_pkrtz(pl * vy0w, pr * vy0w));
        unsigned wb = pk2u(__builtin_amdgcn_cvt_pkrtz(pl * vy1w, pr * vy1w));
        s_wi[lp * 33 + ql] = make_int4((int)wt, (int)wb, otop, obot);
    }
    __syncthreads();

    const int ql  = tid >> 3;          // 0..31
    const int l8  = tid & 7;
    const int dby = l8 * 16;           // byte offset of this lane's 4-dim pair block

    if (q0b + ql < LQ) {
        const char* plane = (const char*)(vperm + (size_t)(b * NH + h) * PLANE_USH);
        float a0 = 0.f, a1 = 0.f, a2 = 0.f, a3 = 0.f;
        #pragma unroll
        for (int pt = 0; pt < 16; pt++) {
            int4 wi = s_wi[pt * 33 + ql];
            uint4 vt = *(const uint4*)(plane + (unsigned)(wi.z + dby));
            uint4 vb = *(const uint4*)(plane + (unsigned)(wi.w + dby));
            half2_t wt = ash2((unsigned)wi.x);
            half2_t wb = ash2((unsigned)wi.y);
            a0 = __builtin_amdgcn_fdot2(wt, ash2(vt.x), a0, false);
            a0 = __builtin_amdgcn_fdot2(wb, ash2(vb.x), a0, false);
            a1 = __builtin_amdgcn_fdot2(wt, ash2(vt.y), a1, false);
            a1 = __builtin_amdgcn_fdot2(wb, ash2(vb.y), a1, false);
            a2 = __builtin_amdgcn_fdot2(wt, ash2(vt.z), a2, false);
            a2 = __builtin_amdgcn_fdot2(wb, ash2(vb.z), a2, false);
            a3 = __builtin_amdgcn_fdot2(wt, ash2(vt.w), a3, false);
            a3 = __builtin_amdgcn_fdot2(wb, ash2(vb.w), a3, false);
        }
        const size_t bq = bq0 + ql;
        ushort4 o;
        o.x = f2bf(a0); o.y = f2bf(a1);
        o.z = f2bf(a2); o.w = f2bf(a3);
        *(ushort4*)(sampled + bq * 256 + h * 32 + l8 * 4) = o;
    }
}

extern "C" void kernel_launch(void* const* d_in, const int* in_sizes, int n_in,
                              void* d_out, int out_size, void* d_ws, size_t ws_size,
                              hipStream_t stream) {
    const float* query = (const float*)d_in[0];
    const float* refp  = (const float*)d_in[1];
    const float* value = (const float*)d_in[2];
    const float* Wv    = (const float*)d_in[4];
    const float* bv    = (const float*)d_in[5];
    const float* Woff  = (const float*)d_in[6];
    const float* boff  = (const float*)d_in[7];
    const float* Wattn = (const float*)d_in[8];
    const float* battn = (const float*)d_in[9];
    const float* Wo    = (const float*)d_in[10];
    const float* bo    = (const float*)d_in[11];
    float* out = (float*)d_out;

    // Workspace (95.7 MB): off 17.2 + awl 8.6 + value_b 17.4 + query_b 17.2
    //                      + vperm(pair x2) 34.8 + BT 0.46
    ushort_t* ws = (ushort_t*)d_ws;
    ushort_t* off_b   = ws;                       // 33600*256
    ushort_t* awl_b   = off_b + 8601600;          // 33600*128
    ushort_t* value_b = awl_b + 4300800;          // 34000*256
    ushort_t* query_b = value_b + 8704000;        // 33600*256 (aliased w/ sampled)
    ushort_t* vperm_b = query_b + 8601600;        // 32 planes * 544000 (f16 pairs)
    ushort_t* BT      = vperm_b + 17408000;       // 896*256
    ushort_t* sampled_b = query_b;                // alias: query dead after gemm_fused

    prep_all<<<dim3(17796), 256, 0, stream>>>(
        value, query, Wv, Woff, Wattn, Wo, value_b, query_b, BT);

    gemm_fused<<<dim3(266 + 396), 512, 0, stream>>>(
        value_b, query_b, BT, bv, boff, battn, vperm_b, off_b, awl_b);

    msda_sample<<<dim3(8 * 4 * 263), 256, 0, stream>>>(
        vperm_b, off_b, awl_b, refp, sampled_b);

    gemm_out<<<dim3(264), 512, 0, stream>>>(
        sampled_b, BT + 163840, bo, out);
}